// Round 10
// baseline (453.414 us; speedup 1.0000x reference)
//
#include <hip/hip_runtime.h>

#define NN_NODES 100000
#define NN_EDGES 50000
#define DD 128
#define NNZP 1600000
#define NT_SEG (NN_EDGES + NN_NODES)   // 150000 segments (edges first, then nodes)
#define TOTP (2 * NNZP)                // 3.2M (seg,val) pairs across both directions
#define BKT_SHIFT 9                    // 512 segments per bucket
#define NBKT ((NT_SEG + 511) / 512)    // 293
#define TILE 8192
#define NBIN ((TOTP + TILE - 1) / TILE)  // 391
#define CVTBLK 1024
#define SMAX 18432
#define CAP 20480                      // fixed bucket staging capacity (~32 sigma margin)
#define VMASK 0xFFFFF                  // 20-bit value field in packed staging

typedef unsigned int uint;
typedef unsigned short ushort;
typedef __attribute__((ext_vector_type(8))) short bf16x8;
typedef __attribute__((ext_vector_type(4))) float f32x4;

__device__ __forceinline__ float bf_lo(uint u) {
  union { uint i; float f; } c; c.i = u << 16; return c.f;
}
__device__ __forceinline__ float bf_hi(uint u) {
  union { uint i; float f; } c; c.i = u & 0xffff0000u; return c.f;
}
__device__ __forceinline__ ushort f2bf(float f) {   // round-to-nearest-even
  union { float f; uint i; } c; c.f = f;
  uint r = c.i + 0x7fffu + ((c.i >> 16) & 1u);
  return (ushort)(r >> 16);
}

// ---------- exclusive block scan over 512 ints, 512 threads ----------
__device__ __forceinline__ void block_excl_scan_512(const int* __restrict__ arr,
                                                    int* __restrict__ out,
                                                    int* __restrict__ wsum) {
  int t = threadIdx.x;
  int v = arr[t];
  int lane = t & 63, wid = t >> 6;
  int s = v;
  #pragma unroll
  for (int o = 1; o < 64; o <<= 1) {
    int u = __shfl_up(s, o, 64);
    if (lane >= o) s += u;
  }
  if (lane == 63) wsum[wid] = s;
  __syncthreads();
  int add = 0;
  for (int w = 0; w < wid; ++w) add += wsum[w];
  out[t] = s + add - v;
}

// ---------- fused: bin pairs (packed staging) + X->bf16 + Wc/bc compose ----------
__global__ __launch_bounds__(512) void k_bin(const int* __restrict__ ninc,
                                             const int* __restrict__ einc,
                                             int* __restrict__ bktcur,
                                             int* __restrict__ pbuf,
                                             const float* __restrict__ X,
                                             ushort* __restrict__ Xb,
                                             const float* __restrict__ W1,
                                             const float* __restrict__ W2,
                                             const float* __restrict__ b1,
                                             const float* __restrict__ b2,
                                             ushort* __restrict__ Wct,
                                             float* __restrict__ bc) {
  __shared__ int spack[TILE];          // 32 KB (also reused as W1 stage in wc branch)
  __shared__ ushort sbkt[TILE];        // 16 KB
  __shared__ int bhist[512], bexcl[512], bcur[512], brun[512], wsum[8];
  const int b = blockIdx.x;
  const int t = threadIdx.x;
  if (b >= NBIN + CVTBLK) {
    // ---- Wc = W1@W2 (bf16 [c][k]) + bc = b1@W2 + b2 ----
    const int bb = b - NBIN - CVTBLK;  // 0..15, W1-rows [8bb, 8bb+8)
    float* sW1 = (float*)spack;        // 8x128 floats = 4 KB
    for (int i = t; i < 8 * 32; i += 512)
      reinterpret_cast<float4*>(sW1)[i] = reinterpret_cast<const float4*>(W1 + bb * 8 * DD)[i];
    __syncthreads();
    if (t < 256) {
      const int lr = t >> 5;           // local row 0..7
      const int cg = t & 31;           // col group (4 cols)
      float s0 = 0.f, s1 = 0.f, s2 = 0.f, s3 = 0.f;
      for (int j = 0; j < DD; ++j) {
        float a = sW1[lr * DD + j];
        float4 w = reinterpret_cast<const float4*>(W2)[j * 32 + cg];
        s0 += a * w.x; s1 += a * w.y; s2 += a * w.z; s3 += a * w.w;
      }
      const int grow = bb * 8 + lr;    // k-index in Wct[c][k]
      const int c0 = cg * 4;
      Wct[(size_t)(c0 + 0) * DD + grow] = f2bf(s0);
      Wct[(size_t)(c0 + 1) * DD + grow] = f2bf(s1);
      Wct[(size_t)(c0 + 2) * DD + grow] = f2bf(s2);
      Wct[(size_t)(c0 + 3) * DD + grow] = f2bf(s3);
    }
    if (bb == 0 && t >= 256 && t < 256 + DD) {
      int c = t - 256;
      float s = b2[c];
      for (int j = 0; j < DD; ++j) s += b1[j] * W2[(size_t)j * DD + c];
      bc[c] = s;
    }
    return;
  }
  if (b >= NBIN) {
    // ---- X -> bf16 convert (no syncthreads) ----
    const int stride = CVTBLK * 512;
    for (int i = (b - NBIN) * 512 + t; i < NN_NODES * DD / 4; i += stride) {
      float4 v = reinterpret_cast<const float4*>(X)[i];
      ushort4 o;
      o.x = f2bf(v.x); o.y = f2bf(v.y); o.z = f2bf(v.z); o.w = f2bf(v.w);
      reinterpret_cast<ushort4*>(Xb)[i] = o;
    }
    return;
  }
  // ---- binning ----
  const int i0 = b * TILE;
  const int V = min(TILE, TOTP - i0);
  int pseg[16], pval[16];
  bhist[t] = 0;
  __syncthreads();
  #pragma unroll
  for (int j = 0; j < 16; ++j) {
    int e = t + j * 512;
    if (e < V) {
      int i = i0 + e;
      int seg, val;
      if (i < NNZP) { seg = einc[i]; val = ninc[i]; }
      else          { seg = NN_EDGES + ninc[i - NNZP]; val = einc[i - NNZP]; }
      pseg[j] = seg; pval[j] = val;
      atomicAdd(&bhist[seg >> BKT_SHIFT], 1);
    }
  }
  __syncthreads();
  block_excl_scan_512(bhist, bexcl, wsum);
  __syncthreads();
  if (t < NBKT && bhist[t] > 0)
    brun[t] = t * CAP + atomicAdd(&bktcur[t], bhist[t]);
  bcur[t] = bexcl[t];
  __syncthreads();
  #pragma unroll
  for (int j = 0; j < 16; ++j) {
    int e = t + j * 512;
    if (e < V) {
      int bk = pseg[j] >> BKT_SHIFT;
      int slot = atomicAdd(&bcur[bk], 1);
      spack[slot] = ((pseg[j] & 511) << 20) | pval[j];
      sbkt[slot] = (ushort)bk;
    }
  }
  __syncthreads();
  for (int e = t; e < V; e += 512) {
    int bk = sbkt[e];
    int gpos = brun[bk] + (e - bexcl[bk]);
    if (gpos < (bk + 1) * CAP)           // OOB guard (statistically unreachable)
      pbuf[gpos] = spack[e];
  }
}

// ---------- per-bucket placement: inline base scan + offs + list + deg-hist ----------
__global__ __launch_bounds__(512) void k_place(const int* __restrict__ bktcnt,
                                               const int* __restrict__ pbuf,
                                               int* __restrict__ offs,
                                               int* __restrict__ list,
                                               int* __restrict__ dhist) {
  __shared__ int shist[512], sexcl[512], scur[512], wsum[8], red[8];
  __shared__ int stage[SMAX];
  const int b = blockIdx.x;
  const int t = threadIdx.x;
  // base = sum_{i<b} min(cnt[i],CAP)
  int part = 0;
  for (int i = t; i < b; i += 512) part += min(bktcnt[i], CAP);
  #pragma unroll
  for (int o = 1; o < 64; o <<= 1) part += __shfl_xor(part, o, 64);
  if ((t & 63) == 0) red[t >> 6] = part;
  shist[t] = 0;
  __syncthreads();
  int base = 0;
  #pragma unroll
  for (int w = 0; w < 8; ++w) base += red[w];
  const int sb = b * CAP;
  const int s = min(bktcnt[b], CAP);
  for (int e = t; e < s; e += 512) atomicAdd(&shist[pbuf[sb + e] >> 20], 1);
  __syncthreads();
  // degree-class histogram for the scheduling sort (shist[t] == degree of seg)
  {
    int segg = (b << BKT_SHIFT) + t;
    if (segg < NT_SEG) {
      int region = (segg < NN_EDGES) ? 0 : 1;
      int bin = region * 256 + (255 - min(shist[t], 255));   // descending degree
      atomicAdd(&dhist[bin], 1);
    }
  }
  block_excl_scan_512(shist, sexcl, wsum);
  __syncthreads();
  int seg = (b << BKT_SHIFT) + t;
  if (seg < NT_SEG) offs[seg] = base + sexcl[t];
  if (b == 0 && t == 0) offs[NT_SEG] = TOTP;
  scur[t] = sexcl[t];
  __syncthreads();
  if (s <= SMAX) {
    for (int e = t; e < s; e += 512) {
      int p = pbuf[sb + e];
      int slot = atomicAdd(&scur[p >> 20], 1);
      stage[slot] = p & VMASK;
    }
    __syncthreads();
    for (int e = t; e < s; e += 512) list[base + e] = stage[e];
  } else {
    for (int e = t; e < s; e += 512) {
      int p = pbuf[sb + e];
      int r = atomicAdd(&scur[p >> 20], 1);
      list[base + r] = p & VMASK;
    }
  }
}

// ---------- degree-class base scan (1 block, 512 threads) ----------
__global__ void k_dscan(const int* __restrict__ dhist, int* __restrict__ dcur) {
  __shared__ int arr[512], out[512], wsum[8];
  int t = threadIdx.x;
  arr[t] = dhist[t];
  __syncthreads();
  block_excl_scan_512(arr, out, wsum);
  __syncthreads();
  dcur[t] = out[t];      // edge bins land in [0,50000), node bins in [50000,150000)
}

// ---------- scatter segments into degree-sorted perm (tile-reserved runs) ----------
__global__ __launch_bounds__(512) void k_dscat(const int* __restrict__ offs,
                                               int* __restrict__ dcur,
                                               int* __restrict__ perm) {
  __shared__ int bhist[512], brun[512], bcur[512];
  const int t = threadIdx.x;
  const int i = blockIdx.x * 512 + t;
  bhist[t] = 0; bcur[t] = 0;
  __syncthreads();
  int bin = 0;
  const bool valid = (i < NT_SEG);
  if (valid) {
    int dg = offs[i + 1] - offs[i];
    int region = (i < NN_EDGES) ? 0 : 1;
    bin = region * 256 + (255 - min(dg, 255));
    atomicAdd(&bhist[bin], 1);
  }
  __syncthreads();
  if (bhist[t] > 0) brun[t] = atomicAdd(&dcur[t], bhist[t]);
  __syncthreads();
  if (valid) {
    int r = atomicAdd(&bcur[bin], 1);
    perm[brun[bin] + r] = (i < NN_EDGES) ? i : i - NN_EDGES;   // local id
  }
}

// ---------- segment mean gather: DS-free, deg-sorted schedule, 8-deep feed ----------
// 16 lanes/segment, uint4 row loads (256 B/row). Segment ids come from perm so
// groups co-resident in a wave have near-equal degrees (no drained-lane waste).
// MODE 0: write bf16 row. MODE 1: fused epilogue — +bias*gate, relu, fp32 out.
#define ACC8(V) do { \
    acc[0] += bf_lo(V.x); acc[1] += bf_hi(V.x); \
    acc[2] += bf_lo(V.y); acc[3] += bf_hi(V.y); \
    acc[4] += bf_lo(V.z); acc[5] += bf_hi(V.z); \
    acc[6] += bf_lo(V.w); acc[7] += bf_hi(V.w); } while (0)

template<int MODE>
__global__ __launch_bounds__(256) void k_agg(const ushort* __restrict__ src,
                                             void* __restrict__ dstv,
                                             const float* __restrict__ bias,
                                             const int* __restrict__ offs,
                                             const int* __restrict__ list,
                                             const int* __restrict__ perm,
                                             int nseg, int segbase) {
  int g = (int)((blockIdx.x * blockDim.x + threadIdx.x) >> 4);
  int t = threadIdx.x & 15;
  if (g >= nseg) return;
  int p = perm[segbase + g];
  int b0 = offs[segbase + p];
  int deg = offs[segbase + p + 1] - b0;
  float acc[8];
  #pragma unroll
  for (int j = 0; j < 8; ++j) acc[j] = 0.f;
  const int* lp = list + b0;
  int ida[8];
  #pragma unroll
  for (int j = 0; j < 8; ++j) ida[j] = lp[j];
  int chunk = 0;
  while (chunk + 8 <= deg) {
    uint4 vb[8];
    #pragma unroll
    for (int j = 0; j < 8; ++j)
      vb[j] = reinterpret_cast<const uint4*>(src + (size_t)ida[j] * DD)[t];
    int idb[8];
    #pragma unroll
    for (int j = 0; j < 8; ++j) idb[j] = lp[chunk + 8 + j];
    #pragma unroll
    for (int j = 0; j < 8; ++j) ACC8(vb[j]);
    #pragma unroll
    for (int j = 0; j < 8; ++j) ida[j] = idb[j];
    chunk += 8;
  }
  if (chunk < deg) {
    uint4 vb[8];
    #pragma unroll
    for (int j = 0; j < 8; ++j) {
      uint4 v = make_uint4(0u, 0u, 0u, 0u);
      if (chunk + j < deg)
        v = reinterpret_cast<const uint4*>(src + (size_t)ida[j] * DD)[t];
      vb[j] = v;
    }
    #pragma unroll
    for (int j = 0; j < 8; ++j) ACC8(vb[j]);
  }
  float inv = 1.0f / fmaxf((float)deg, 1.0f);
  if (MODE == 0) {
    ushort* dst = (ushort*)dstv;
    uint4 o;
    o.x = (uint)f2bf(acc[0] * inv) | ((uint)f2bf(acc[1] * inv) << 16);
    o.y = (uint)f2bf(acc[2] * inv) | ((uint)f2bf(acc[3] * inv) << 16);
    o.z = (uint)f2bf(acc[4] * inv) | ((uint)f2bf(acc[5] * inv) << 16);
    o.w = (uint)f2bf(acc[6] * inv) | ((uint)f2bf(acc[7] * inv) << 16);
    reinterpret_cast<uint4*>(dst + (size_t)p * DD)[t] = o;
  } else {
    float flag = (deg > 0) ? 1.f : 0.f;
    float4 bb0 = reinterpret_cast<const float4*>(bias)[2 * t];
    float4 bb1 = reinterpret_cast<const float4*>(bias)[2 * t + 1];
    float4 o0, o1;
    o0.x = fmaxf(acc[0] * inv + bb0.x * flag, 0.f);
    o0.y = fmaxf(acc[1] * inv + bb0.y * flag, 0.f);
    o0.z = fmaxf(acc[2] * inv + bb0.z * flag, 0.f);
    o0.w = fmaxf(acc[3] * inv + bb0.w * flag, 0.f);
    o1.x = fmaxf(acc[4] * inv + bb1.x * flag, 0.f);
    o1.y = fmaxf(acc[5] * inv + bb1.y * flag, 0.f);
    o1.z = fmaxf(acc[6] * inv + bb1.z * flag, 0.f);
    o1.w = fmaxf(acc[7] * inv + bb1.w * flag, 0.f);
    float* orow = (float*)dstv + (size_t)p * DD;
    reinterpret_cast<float4*>(orow)[2 * t] = o0;
    reinterpret_cast<float4*>(orow)[2 * t + 1] = o1;
  }
}

// ---------- MFMA bf16 GEMM: C[M,128] = A[M,128] @ W (in-place, bf16 out) ----------
__global__ __launch_bounds__(256) void k_gemm_mfma(
    const ushort* __restrict__ A, ushort* __restrict__ C,
    const ushort* __restrict__ Wt, int M) {
  __shared__ ushort sA[DD * DD];   // 32 KB, XOR-swizzled rows (256 B each)
  __shared__ ushort sW[DD * DD];   // 32 KB
  const int tid = threadIdx.x;
  const int R = blockIdx.x * DD;
  const int rows = min(DD, M - R);
  for (int i = tid; i < DD * 16; i += 256) {
    int r = i >> 4, c8 = i & 15;
    uint4 v = reinterpret_cast<const uint4*>(Wt + (size_t)r * DD)[c8];
    int bo = (c8 * 16) ^ ((r & 7) << 4);
    *reinterpret_cast<uint4*>(reinterpret_cast<char*>(sW) + r * 256 + bo) = v;
  }
  for (int i = tid; i < DD * 16; i += 256) {
    int r = i >> 4, c8 = i & 15;
    uint4 v = make_uint4(0u, 0u, 0u, 0u);
    if (r < rows) v = reinterpret_cast<const uint4*>(A + (size_t)(R + r) * DD)[c8];
    int bo = (c8 * 16) ^ ((r & 7) << 4);
    *reinterpret_cast<uint4*>(reinterpret_cast<char*>(sA) + r * 256 + bo) = v;
  }
  __syncthreads();
  const int wid = tid >> 6;
  const int l = tid & 63;
  const int lr = l & 15;
  const int lg = l >> 4;
  const int wrow = wid * 32;
  f32x4 acc[2][8];
  #pragma unroll
  for (int a = 0; a < 2; ++a)
    #pragma unroll
    for (int b = 0; b < 8; ++b) acc[a][b] = (f32x4){0.f, 0.f, 0.f, 0.f};
  const char* cA = reinterpret_cast<const char*>(sA);
  const char* cW = reinterpret_cast<const char*>(sW);
  #pragma unroll
  for (int k0 = 0; k0 < 4; ++k0) {
    int kb = k0 * 64 + lg * 16;
    int r0 = wrow + lr, r1 = wrow + 16 + lr;
    bf16x8 a0 = *reinterpret_cast<const bf16x8*>(cA + r0 * 256 + (kb ^ ((r0 & 7) << 4)));
    bf16x8 a1 = *reinterpret_cast<const bf16x8*>(cA + r1 * 256 + (kb ^ ((r1 & 7) << 4)));
    bf16x8 bfr[8];
    #pragma unroll
    for (int ct = 0; ct < 8; ++ct) {
      int c = ct * 16 + lr;
      bfr[ct] = *reinterpret_cast<const bf16x8*>(cW + c * 256 + (kb ^ ((c & 7) << 4)));
    }
    #pragma unroll
    for (int ct = 0; ct < 8; ++ct) {
      acc[0][ct] = __builtin_amdgcn_mfma_f32_16x16x32_bf16(a0, bfr[ct], acc[0][ct], 0, 0, 0);
      acc[1][ct] = __builtin_amdgcn_mfma_f32_16x16x32_bf16(a1, bfr[ct], acc[1][ct], 0, 0, 0);
    }
  }
  #pragma unroll
  for (int rt = 0; rt < 2; ++rt) {
    #pragma unroll
    for (int j = 0; j < 4; ++j) {
      int r = wrow + rt * 16 + lg * 4 + j;
      if (r < rows) {
        int gr = R + r;
        #pragma unroll
        for (int ct = 0; ct < 8; ++ct)
          C[(size_t)gr * DD + ct * 16 + lr] = f2bf(acc[rt][ct][j]);
      }
    }
  }
}

extern "C" void kernel_launch(void* const* d_in, const int* in_sizes, int n_in,
                              void* d_out, int out_size, void* d_ws, size_t ws_size,
                              hipStream_t stream) {
  const float* X   = (const float*)d_in[1];
  const int*   inc = (const int*)d_in[2];
  const float* W1  = (const float*)d_in[3];
  const float* b1  = (const float*)d_in[4];
  const float* W2  = (const float*)d_in[5];
  const float* b2  = (const float*)d_in[6];
  float* out = (float*)d_out;
  const int* ninc = inc;
  const int* einc = inc + NNZP;

  // workspace carve-up (~64 MB)
  char* wsp = (char*)d_ws;
  int* pbuf    = (int*)wsp;    wsp += (size_t)NBKT * CAP * sizeof(int);        // 24.0 MB packed staging
  ushort* Xb   = (ushort*)wsp; wsp += (size_t)NN_NODES * DD * sizeof(ushort);  // 25.6 MB X bf16
  int* offs    = (int*)wsp;    wsp += (size_t)(NT_SEG + 1) * sizeof(int);      // 0.6 MB
  int* list    = (int*)wsp;    wsp += (size_t)TOTP * sizeof(int);              // 12.8 MB
  int* perm    = (int*)wsp;    wsp += (size_t)NT_SEG * sizeof(int);            // 0.6 MB
  int* bktcur  = (int*)wsp;    wsp += 512 * sizeof(int);
  int* dhist   = (int*)wsp;    wsp += 512 * sizeof(int);
  int* dcur    = (int*)wsp;    wsp += 512 * sizeof(int);
  ushort* Wct  = (ushort*)wsp; wsp += (size_t)DD * DD * sizeof(ushort);        // 32 KB
  float* bc    = (float*)wsp;  wsp += DD * sizeof(float);
  // E / E' buffer aliases the head of staging (staging dead after k_place)
  ushort* bufE = (ushort*)pbuf;                                                // 12.8 MB

  hipMemsetAsync(bktcur, 0, 1024 * sizeof(int), stream);   // bktcur + dhist

  // fused: bin into fixed-cap packed staging + X->bf16 + Wc/bc compose
  k_bin<<<NBIN + CVTBLK + 16, 512, 0, stream>>>(ninc, einc, bktcur, pbuf,
                                                X, Xb, W1, W2, b1, b2, Wct, bc);
  // compact into final CSR (offs + list) + degree-class histogram
  k_place<<<NBKT, 512, 0, stream>>>(bktcur, pbuf, offs, list, dhist);
  // degree-sorted scheduling permutation
  k_dscan<<<1, 512, 0, stream>>>(dhist, dcur);
  k_dscat<<<(NT_SEG + 511) / 512, 512, 0, stream>>>(offs, dcur, perm);

  // E[e] = mean_{n in e} Xb[n]  (bf16)
  k_agg<0><<<(NN_EDGES * 16 + 255) / 256, 256, 0, stream>>>(Xb, bufE, nullptr, offs, list, perm, NN_EDGES, 0);
  // E' = E @ Wc  (50k rows, in-place bf16, MFMA)
  k_gemm_mfma<<<(NN_EDGES + DD - 1) / DD, 256, 0, stream>>>(bufE, bufE, Wct, NN_EDGES);
  // out[n] = relu(mean_{e ni n} E'[e] + bc*gate)  (fp32, fused epilogue)
  k_agg<1><<<(NN_NODES * 16 + 255) / 256, 256, 0, stream>>>(bufE, out, bc, offs, list, perm, NN_NODES, NN_EDGES);
}

// Round 11
// 174.089 us; speedup vs baseline: 2.6045x; 2.6045x over previous
//
#include <hip/hip_runtime.h>

#define NN_NODES 100000
#define NN_EDGES 50000
#define DD 128
#define NNZP 1600000
#define NT_SEG (NN_EDGES + NN_NODES)   // 150000 segments (edges first, then nodes)
#define TOTP (2 * NNZP)                // 3.2M (seg,val) pairs across both directions
#define BKT_SHIFT 9                    // 512 segments per bucket
#define NBKT ((NT_SEG + 511) / 512)    // 293
#define TILE 8192
#define NBIN ((TOTP + TILE - 1) / TILE)  // 391
#define CVTBLK 1024
#define SMAX 18432
#define CAP 20480                      // fixed bucket staging capacity (~32 sigma margin)
#define VMASK 0xFFFFF                  // 20-bit value field in packed staging

typedef unsigned int uint;
typedef unsigned short ushort;
typedef __attribute__((ext_vector_type(8))) short bf16x8;
typedef __attribute__((ext_vector_type(4))) float f32x4;

__device__ __forceinline__ float bf_lo(uint u) {
  union { uint i; float f; } c; c.i = u << 16; return c.f;
}
__device__ __forceinline__ float bf_hi(uint u) {
  union { uint i; float f; } c; c.i = u & 0xffff0000u; return c.f;
}
__device__ __forceinline__ ushort f2bf(float f) {   // round-to-nearest-even
  union { float f; uint i; } c; c.f = f;
  uint r = c.i + 0x7fffu + ((c.i >> 16) & 1u);
  return (ushort)(r >> 16);
}

// ---------- exclusive block scan over 512 ints, 512 threads ----------
__device__ __forceinline__ void block_excl_scan_512(const int* __restrict__ arr,
                                                    int* __restrict__ out,
                                                    int* __restrict__ wsum) {
  int t = threadIdx.x;
  int v = arr[t];
  int lane = t & 63, wid = t >> 6;
  int s = v;
  #pragma unroll
  for (int o = 1; o < 64; o <<= 1) {
    int u = __shfl_up(s, o, 64);
    if (lane >= o) s += u;
  }
  if (lane == 63) wsum[wid] = s;
  __syncthreads();
  int add = 0;
  for (int w = 0; w < wid; ++w) add += wsum[w];
  out[t] = s + add - v;
}

// ---------- fused: bin pairs (packed staging) + X->bf16 + Wc/bc compose ----------
__global__ __launch_bounds__(512) void k_bin(const int* __restrict__ ninc,
                                             const int* __restrict__ einc,
                                             int* __restrict__ bktcur,
                                             int* __restrict__ pbuf,
                                             const float* __restrict__ X,
                                             ushort* __restrict__ Xb,
                                             const float* __restrict__ W1,
                                             const float* __restrict__ W2,
                                             const float* __restrict__ b1,
                                             const float* __restrict__ b2,
                                             ushort* __restrict__ Wct,
                                             float* __restrict__ bc) {
  __shared__ int spack[TILE];          // 32 KB (also reused as W1 stage in wc branch)
  __shared__ ushort sbkt[TILE];        // 16 KB
  __shared__ int bhist[512], bexcl[512], bcur[512], brun[512], wsum[8];
  const int b = blockIdx.x;
  const int t = threadIdx.x;
  if (b >= NBIN + CVTBLK) {
    // ---- Wc = W1@W2 (bf16 [c][k]) + bc = b1@W2 + b2 ----
    const int bb = b - NBIN - CVTBLK;  // 0..15, W1-rows [8bb, 8bb+8)
    float* sW1 = (float*)spack;        // 8x128 floats = 4 KB
    for (int i = t; i < 8 * 32; i += 512)
      reinterpret_cast<float4*>(sW1)[i] = reinterpret_cast<const float4*>(W1 + bb * 8 * DD)[i];
    __syncthreads();
    if (t < 256) {
      const int lr = t >> 5;           // local row 0..7
      const int cg = t & 31;           // col group (4 cols)
      float s0 = 0.f, s1 = 0.f, s2 = 0.f, s3 = 0.f;
      for (int j = 0; j < DD; ++j) {
        float a = sW1[lr * DD + j];
        float4 w = reinterpret_cast<const float4*>(W2)[j * 32 + cg];
        s0 += a * w.x; s1 += a * w.y; s2 += a * w.z; s3 += a * w.w;
      }
      const int grow = bb * 8 + lr;    // k-index in Wct[c][k]
      const int c0 = cg * 4;
      Wct[(size_t)(c0 + 0) * DD + grow] = f2bf(s0);
      Wct[(size_t)(c0 + 1) * DD + grow] = f2bf(s1);
      Wct[(size_t)(c0 + 2) * DD + grow] = f2bf(s2);
      Wct[(size_t)(c0 + 3) * DD + grow] = f2bf(s3);
    }
    if (bb == 0 && t >= 256 && t < 256 + DD) {
      int c = t - 256;
      float s = b2[c];
      for (int j = 0; j < DD; ++j) s += b1[j] * W2[(size_t)j * DD + c];
      bc[c] = s;
    }
    return;
  }
  if (b >= NBIN) {
    // ---- X -> bf16 convert (no syncthreads) ----
    const int stride = CVTBLK * 512;
    for (int i = (b - NBIN) * 512 + t; i < NN_NODES * DD / 4; i += stride) {
      float4 v = reinterpret_cast<const float4*>(X)[i];
      ushort4 o;
      o.x = f2bf(v.x); o.y = f2bf(v.y); o.z = f2bf(v.z); o.w = f2bf(v.w);
      reinterpret_cast<ushort4*>(Xb)[i] = o;
    }
    return;
  }
  // ---- binning ----
  const int i0 = b * TILE;
  const int V = min(TILE, TOTP - i0);
  int pseg[16], pval[16];
  bhist[t] = 0;
  __syncthreads();
  #pragma unroll
  for (int j = 0; j < 16; ++j) {
    int e = t + j * 512;
    if (e < V) {
      int i = i0 + e;
      int seg, val;
      if (i < NNZP) { seg = einc[i]; val = ninc[i]; }
      else          { seg = NN_EDGES + ninc[i - NNZP]; val = einc[i - NNZP]; }
      pseg[j] = seg; pval[j] = val;
      atomicAdd(&bhist[seg >> BKT_SHIFT], 1);
    }
  }
  __syncthreads();
  block_excl_scan_512(bhist, bexcl, wsum);
  __syncthreads();
  if (t < NBKT && bhist[t] > 0)
    brun[t] = t * CAP + atomicAdd(&bktcur[t], bhist[t]);
  bcur[t] = bexcl[t];
  __syncthreads();
  #pragma unroll
  for (int j = 0; j < 16; ++j) {
    int e = t + j * 512;
    if (e < V) {
      int bk = pseg[j] >> BKT_SHIFT;
      int slot = atomicAdd(&bcur[bk], 1);
      spack[slot] = ((pseg[j] & 511) << 20) | pval[j];
      sbkt[slot] = (ushort)bk;
    }
  }
  __syncthreads();
  for (int e = t; e < V; e += 512) {
    int bk = sbkt[e];
    int gpos = brun[bk] + (e - bexcl[bk]);
    if (gpos < (bk + 1) * CAP)           // OOB guard (statistically unreachable)
      pbuf[gpos] = spack[e];
  }
}

// ---------- per-bucket placement: inline base scan + offs + final list ----------
__global__ __launch_bounds__(512) void k_place(const int* __restrict__ bktcnt,
                                               const int* __restrict__ pbuf,
                                               int* __restrict__ offs,
                                               int* __restrict__ list) {
  __shared__ int shist[512], sexcl[512], scur[512], wsum[8], red[8];
  __shared__ int stage[SMAX];
  const int b = blockIdx.x;
  const int t = threadIdx.x;
  // base = sum_{i<b} min(cnt[i],CAP)
  int part = 0;
  for (int i = t; i < b; i += 512) part += min(bktcnt[i], CAP);
  #pragma unroll
  for (int o = 1; o < 64; o <<= 1) part += __shfl_xor(part, o, 64);
  if ((t & 63) == 0) red[t >> 6] = part;
  shist[t] = 0;
  __syncthreads();
  int base = 0;
  #pragma unroll
  for (int w = 0; w < 8; ++w) base += red[w];
  const int sb = b * CAP;
  const int s = min(bktcnt[b], CAP);
  for (int e = t; e < s; e += 512) atomicAdd(&shist[pbuf[sb + e] >> 20], 1);
  __syncthreads();
  block_excl_scan_512(shist, sexcl, wsum);
  __syncthreads();
  int seg = (b << BKT_SHIFT) + t;
  if (seg < NT_SEG) offs[seg] = base + sexcl[t];
  if (b == 0 && t == 0) offs[NT_SEG] = TOTP;
  scur[t] = sexcl[t];
  __syncthreads();
  if (s <= SMAX) {
    for (int e = t; e < s; e += 512) {
      int p = pbuf[sb + e];
      int slot = atomicAdd(&scur[p >> 20], 1);
      stage[slot] = p & VMASK;
    }
    __syncthreads();
    for (int e = t; e < s; e += 512) list[base + e] = stage[e];
  } else {
    for (int e = t; e < s; e += 512) {
      int p = pbuf[sb + e];
      int r = atomicAdd(&scur[p >> 20], 1);
      list[base + r] = p & VMASK;
    }
  }
}

// ---------- segment mean gather: DS-free, double-buffered index feed ----------
// 16 lanes/segment, uint4 row loads (256 B/row). Indices loaded as uniform
// per-lane global loads (HW broadcast). 8 rows + next 8 indices in flight.
// MODE 0: write bf16 row. MODE 1: fused epilogue — +bias*gate, relu, fp32 out.
#define ACC8(V) do { \
    acc[0] += bf_lo(V.x); acc[1] += bf_hi(V.x); \
    acc[2] += bf_lo(V.y); acc[3] += bf_hi(V.y); \
    acc[4] += bf_lo(V.z); acc[5] += bf_hi(V.z); \
    acc[6] += bf_lo(V.w); acc[7] += bf_hi(V.w); } while (0)

template<int MODE>
__global__ __launch_bounds__(256) void k_agg(const ushort* __restrict__ src,
                                             void* __restrict__ dstv,
                                             const float* __restrict__ bias,
                                             const int* __restrict__ offs,
                                             const int* __restrict__ list,
                                             int nseg, int segbase) {
  int g = (int)((blockIdx.x * blockDim.x + threadIdx.x) >> 4);
  int t = threadIdx.x & 15;
  if (g >= nseg) return;
  int b0 = offs[segbase + g];
  int deg = offs[segbase + g + 1] - b0;
  float acc[8];
  #pragma unroll
  for (int j = 0; j < 8; ++j) acc[j] = 0.f;
  const int* lp = list + b0;
  int ida[8];
  #pragma unroll
  for (int j = 0; j < 8; ++j) ida[j] = lp[j];
  int chunk = 0;
  while (chunk + 8 <= deg) {
    uint4 vb[8];
    #pragma unroll
    for (int j = 0; j < 8; ++j)
      vb[j] = reinterpret_cast<const uint4*>(src + (size_t)ida[j] * DD)[t];
    int idb[8];
    #pragma unroll
    for (int j = 0; j < 8; ++j) idb[j] = lp[chunk + 8 + j];
    #pragma unroll
    for (int j = 0; j < 8; ++j) ACC8(vb[j]);
    #pragma unroll
    for (int j = 0; j < 8; ++j) ida[j] = idb[j];
    chunk += 8;
  }
  if (chunk < deg) {
    uint4 vb[8];
    #pragma unroll
    for (int j = 0; j < 8; ++j) {
      uint4 v = make_uint4(0u, 0u, 0u, 0u);
      if (chunk + j < deg)
        v = reinterpret_cast<const uint4*>(src + (size_t)ida[j] * DD)[t];
      vb[j] = v;
    }
    #pragma unroll
    for (int j = 0; j < 8; ++j) ACC8(vb[j]);
  }
  float inv = 1.0f / fmaxf((float)deg, 1.0f);
  if (MODE == 0) {
    ushort* dst = (ushort*)dstv;
    uint4 o;
    o.x = (uint)f2bf(acc[0] * inv) | ((uint)f2bf(acc[1] * inv) << 16);
    o.y = (uint)f2bf(acc[2] * inv) | ((uint)f2bf(acc[3] * inv) << 16);
    o.z = (uint)f2bf(acc[4] * inv) | ((uint)f2bf(acc[5] * inv) << 16);
    o.w = (uint)f2bf(acc[6] * inv) | ((uint)f2bf(acc[7] * inv) << 16);
    reinterpret_cast<uint4*>(dst + (size_t)g * DD)[t] = o;
  } else {
    float flag = (deg > 0) ? 1.f : 0.f;
    float4 bb0 = reinterpret_cast<const float4*>(bias)[2 * t];
    float4 bb1 = reinterpret_cast<const float4*>(bias)[2 * t + 1];
    float4 o0, o1;
    o0.x = fmaxf(acc[0] * inv + bb0.x * flag, 0.f);
    o0.y = fmaxf(acc[1] * inv + bb0.y * flag, 0.f);
    o0.z = fmaxf(acc[2] * inv + bb0.z * flag, 0.f);
    o0.w = fmaxf(acc[3] * inv + bb0.w * flag, 0.f);
    o1.x = fmaxf(acc[4] * inv + bb1.x * flag, 0.f);
    o1.y = fmaxf(acc[5] * inv + bb1.y * flag, 0.f);
    o1.z = fmaxf(acc[6] * inv + bb1.z * flag, 0.f);
    o1.w = fmaxf(acc[7] * inv + bb1.w * flag, 0.f);
    float* orow = (float*)dstv + (size_t)g * DD;
    reinterpret_cast<float4*>(orow)[2 * t] = o0;
    reinterpret_cast<float4*>(orow)[2 * t + 1] = o1;
  }
}

// ---------- MFMA bf16 GEMM: C[M,128] = A[M,128] @ W (in-place, bf16 out) ----------
__global__ __launch_bounds__(256) void k_gemm_mfma(
    const ushort* __restrict__ A, ushort* __restrict__ C,
    const ushort* __restrict__ Wt, int M) {
  __shared__ ushort sA[DD * DD];   // 32 KB, XOR-swizzled rows (256 B each)
  __shared__ ushort sW[DD * DD];   // 32 KB
  const int tid = threadIdx.x;
  const int R = blockIdx.x * DD;
  const int rows = min(DD, M - R);
  for (int i = tid; i < DD * 16; i += 256) {
    int r = i >> 4, c8 = i & 15;
    uint4 v = reinterpret_cast<const uint4*>(Wt + (size_t)r * DD)[c8];
    int bo = (c8 * 16) ^ ((r & 7) << 4);
    *reinterpret_cast<uint4*>(reinterpret_cast<char*>(sW) + r * 256 + bo) = v;
  }
  for (int i = tid; i < DD * 16; i += 256) {
    int r = i >> 4, c8 = i & 15;
    uint4 v = make_uint4(0u, 0u, 0u, 0u);
    if (r < rows) v = reinterpret_cast<const uint4*>(A + (size_t)(R + r) * DD)[c8];
    int bo = (c8 * 16) ^ ((r & 7) << 4);
    *reinterpret_cast<uint4*>(reinterpret_cast<char*>(sA) + r * 256 + bo) = v;
  }
  __syncthreads();
  const int wid = tid >> 6;
  const int l = tid & 63;
  const int lr = l & 15;
  const int lg = l >> 4;
  const int wrow = wid * 32;
  f32x4 acc[2][8];
  #pragma unroll
  for (int a = 0; a < 2; ++a)
    #pragma unroll
    for (int b = 0; b < 8; ++b) acc[a][b] = (f32x4){0.f, 0.f, 0.f, 0.f};
  const char* cA = reinterpret_cast<const char*>(sA);
  const char* cW = reinterpret_cast<const char*>(sW);
  #pragma unroll
  for (int k0 = 0; k0 < 4; ++k0) {
    int kb = k0 * 64 + lg * 16;
    int r0 = wrow + lr, r1 = wrow + 16 + lr;
    bf16x8 a0 = *reinterpret_cast<const bf16x8*>(cA + r0 * 256 + (kb ^ ((r0 & 7) << 4)));
    bf16x8 a1 = *reinterpret_cast<const bf16x8*>(cA + r1 * 256 + (kb ^ ((r1 & 7) << 4)));
    bf16x8 bfr[8];
    #pragma unroll
    for (int ct = 0; ct < 8; ++ct) {
      int c = ct * 16 + lr;
      bfr[ct] = *reinterpret_cast<const bf16x8*>(cW + c * 256 + (kb ^ ((c & 7) << 4)));
    }
    #pragma unroll
    for (int ct = 0; ct < 8; ++ct) {
      acc[0][ct] = __builtin_amdgcn_mfma_f32_16x16x32_bf16(a0, bfr[ct], acc[0][ct], 0, 0, 0);
      acc[1][ct] = __builtin_amdgcn_mfma_f32_16x16x32_bf16(a1, bfr[ct], acc[1][ct], 0, 0, 0);
    }
  }
  #pragma unroll
  for (int rt = 0; rt < 2; ++rt) {
    #pragma unroll
    for (int j = 0; j < 4; ++j) {
      int r = wrow + rt * 16 + lg * 4 + j;
      if (r < rows) {
        int gr = R + r;
        #pragma unroll
        for (int ct = 0; ct < 8; ++ct)
          C[(size_t)gr * DD + ct * 16 + lr] = f2bf(acc[rt][ct][j]);
      }
    }
  }
}

extern "C" void kernel_launch(void* const* d_in, const int* in_sizes, int n_in,
                              void* d_out, int out_size, void* d_ws, size_t ws_size,
                              hipStream_t stream) {
  const float* X   = (const float*)d_in[1];
  const int*   inc = (const int*)d_in[2];
  const float* W1  = (const float*)d_in[3];
  const float* b1  = (const float*)d_in[4];
  const float* W2  = (const float*)d_in[5];
  const float* b2  = (const float*)d_in[6];
  float* out = (float*)d_out;
  const int* ninc = inc;
  const int* einc = inc + NNZP;

  // workspace carve-up (~63 MB)
  char* wsp = (char*)d_ws;
  int* pbuf    = (int*)wsp;    wsp += (size_t)NBKT * CAP * sizeof(int);        // 24.0 MB packed staging
  ushort* Xb   = (ushort*)wsp; wsp += (size_t)NN_NODES * DD * sizeof(ushort);  // 25.6 MB X bf16
  int* offs    = (int*)wsp;    wsp += (size_t)(NT_SEG + 1) * sizeof(int);      // 0.6 MB
  int* list    = (int*)wsp;    wsp += (size_t)TOTP * sizeof(int);              // 12.8 MB
  int* bktcur  = (int*)wsp;    wsp += 512 * sizeof(int);
  ushort* Wct  = (ushort*)wsp; wsp += (size_t)DD * DD * sizeof(ushort);        // 32 KB
  float* bc    = (float*)wsp;  wsp += DD * sizeof(float);
  // E / E' buffer aliases the head of staging (staging dead after k_place)
  ushort* bufE = (ushort*)pbuf;                                                // 12.8 MB

  hipMemsetAsync(bktcur, 0, 512 * sizeof(int), stream);

  // fused: bin into fixed-cap packed staging + X->bf16 + Wc/bc compose
  k_bin<<<NBIN + CVTBLK + 16, 512, 0, stream>>>(ninc, einc, bktcur, pbuf,
                                                X, Xb, W1, W2, b1, b2, Wct, bc);
  // compact into final CSR (offs + list), bucket bases computed inline
  k_place<<<NBKT, 512, 0, stream>>>(bktcur, pbuf, offs, list);

  // E[e] = mean_{n in e} Xb[n]  (bf16)
  k_agg<0><<<(NN_EDGES * 16 + 255) / 256, 256, 0, stream>>>(Xb, bufE, nullptr, offs, list, NN_EDGES, 0);
  // E' = E @ Wc  (50k rows, in-place bf16, MFMA)
  k_gemm_mfma<<<(NN_EDGES + DD - 1) / DD, 256, 0, stream>>>(bufE, bufE, Wct, NN_EDGES);
  // out[n] = relu(mean_{e ni n} E'[e] + bc*gate)  (fp32, fused epilogue)
  k_agg<1><<<(NN_NODES * 16 + 255) / 256, 256, 0, stream>>>(bufE, out, bc, offs, list, NN_NODES, NN_EDGES);
}